// Round 10
// baseline (106.778 us; speedup 1.0000x reference)
//
#include <hip/hip_runtime.h>
#include <math.h>

#define N_SAMP 32768
#define K_COMP 2048
#define ZD 64
#define LNC 191.896324792608546f   // 64*(0.5*log(2pi) + 0.5*log(64))
#define LN2F 0.69314718055994531f
#define INV_LN2 1.44269504088896340f
// w = dot*(1/(64 ln2)) + ck2 ; wlp_nat = w*ln2 + bias_nat
#define S2C 0.02254211001388974f   // 1/(64*ln2)

typedef __attribute__((ext_vector_type(8))) short short8;
typedef __attribute__((ext_vector_type(4))) float v4f;

#if __has_builtin(__builtin_amdgcn_exp2f)
#define EXP2(x) __builtin_amdgcn_exp2f(x)
#else
#define EXP2(x) exp2f(x)
#endif

__device__ inline unsigned short f2bf(float f) {
    unsigned int u = __float_as_uint(f);
    u += 0x7fffu + ((u >> 16) & 1u);  // RNE
    return (unsigned short)(u >> 16);
}

// ---------------------------------------------------------------------------
// prep: blocks 0..63: locs -> bf16-HI fragment array lf (256 KB) + ck2.
//       block 64: lse = logsumexp(logits).
// lf: tile T (16 comps) -> 2 KB: 2 regions {d0-31, d32-63} x 64 lanes x 16 B.
// ---------------------------------------------------------------------------
__global__ __launch_bounds__(256) void prep_kernel(
    const float* __restrict__ locs, const float* __restrict__ logits,
    float* __restrict__ ck2, float* __restrict__ lse_out,
    char* __restrict__ lf) {
    if (blockIdx.x < 64) {
        int gid = blockIdx.x * 256 + threadIdx.x;   // 0..16383
        int k = gid >> 3;
        int dc = gid & 7;
        int T = k >> 4, n = k & 15;

        const float* src = locs + (size_t)k * ZD + dc * 8;
        float4 u0 = *(const float4*)(src);
        float4 u1 = *(const float4*)(src + 4);
        float a[8] = {u0.x, u0.y, u0.z, u0.w, u1.x, u1.y, u1.z, u1.w};

        short8 h;
        float sq = 0.f;
#pragma unroll
        for (int j = 0; j < 8; ++j) {
            h[j] = (short)f2bf(a[j]);
            sq = fmaf(a[j], a[j], sq);
        }
        *(short8*)(lf + (size_t)T * 2048 + (dc >> 2) * 1024 +
                   ((size_t)(n + 16 * (dc & 3))) * 16) = h;

        sq += __shfl_xor(sq, 1);
        sq += __shfl_xor(sq, 2);
        sq += __shfl_xor(sq, 4);
        if (dc == 0) ck2[k] = (logits[k] - sq * (1.0f / 128.0f)) * INV_LN2;
    } else {
        __shared__ float red[4];
        int tid = threadIdx.x;
        int wv = tid >> 6, ln = tid & 63;
        float lm = -INFINITY;
        for (int i = tid; i < K_COMP; i += 256) lm = fmaxf(lm, logits[i]);
#pragma unroll
        for (int d = 1; d < 64; d <<= 1) lm = fmaxf(lm, __shfl_xor(lm, d));
        if (ln == 0) red[wv] = lm;
        __syncthreads();
        float M = fmaxf(fmaxf(red[0], red[1]), fmaxf(red[2], red[3]));
        float ls = 0.f;
        for (int i = tid; i < K_COMP; i += 256) ls += __expf(logits[i] - M);
#pragma unroll
        for (int d = 1; d < 64; d <<= 1) ls += __shfl_xor(ls, d);
        __syncthreads();
        if (ln == 0) red[wv] = ls;
        __syncthreads();
        if (tid == 0) *lse_out = M + __logf(red[0] + red[1] + red[2] + red[3]);
    }
}

// ---------------------------------------------------------------------------
// mix: block = 256 thr = 4 waves = 4 k-groups over the SAME 64 samples
// (every wave holds all 4 sample-tiles' hi-B frags in regs).  Wave kg
// streams tiles kg*32..+31 (64 KB total per wave = minimum traffic) with a
// ROLLED 2-slot register ring (no full unroll -> compiler keeps prefetch
// distance).  Per iter: 3 b128 loads + 8 MFMA (4 indep 2-chains) + 4 EPI
// (flat exp2-sum, provably no overflow + top-3 quad-base).  One barrier,
// LDS merge, exact-fp32 resolution of 12 candidates, gather.
// ---------------------------------------------------------------------------
__global__ __launch_bounds__(256, 2) void mix_kernel(
    const float* __restrict__ x, const float* __restrict__ locs,
    const char* __restrict__ lf, const float* __restrict__ ck2,
    const float* __restrict__ lse_ptr, float* __restrict__ out) {

    __shared__ float pf[4][64][4];   // [kg][samp][{sum,m1,m2,m3}]
    __shared__ int   pi[4][64][4];   // [kg][samp][{i1,i2,i3,pad}]
    __shared__ float xsq_sh[64];
    __shared__ int   cb[3][64];
    __shared__ int   amax_sh[64];

    const int tid  = threadIdx.x;
    const int lane = tid & 63;
    const int kg   = __builtin_amdgcn_readfirstlane(tid >> 6);  // 0..3
    const int n    = lane & 15;
    const int quad = lane >> 4;
    const int sbase = blockIdx.x * 64;

    // ---- B fragments (x, plain bf16) for all 4 sample-tiles; xsq partials
    short8 bh[4][2];
    {
        float p[4];
#pragma unroll
        for (int bt = 0; bt < 4; ++bt) {
            const float* xp = x + (size_t)(sbase + bt * 16 + n) * ZD + quad * 8;
            float4 u0 = *(const float4*)(xp);
            float4 u1 = *(const float4*)(xp + 4);
            float4 u2 = *(const float4*)(xp + 32);
            float4 u3 = *(const float4*)(xp + 36);
            float a[8] = {u0.x, u0.y, u0.z, u0.w, u1.x, u1.y, u1.z, u1.w};
            float b[8] = {u2.x, u2.y, u2.z, u2.w, u3.x, u3.y, u3.z, u3.w};
            float pp = 0.f;
#pragma unroll
            for (int j = 0; j < 8; ++j) {
                bh[bt][0][j] = (short)f2bf(a[j]);
                bh[bt][1][j] = (short)f2bf(b[j]);
                pp = fmaf(a[j], a[j], pp);
                pp = fmaf(b[j], b[j], pp);
            }
            pp += __shfl_xor(pp, 16);
            pp += __shfl_xor(pp, 32);
            p[bt] = pp;
        }
        // lane (quad, n): write xsq of sample quad*16+n (disjoint across lanes)
        if (kg == 0) {
            float myp = (quad == 0) ? p[0] : (quad == 1) ? p[1]
                      : (quad == 2) ? p[2] : p[3];
            xsq_sh[quad * 16 + n] = myp;
        }
    }

    // ---- A stream: wave kg owns tiles kg*32 .. +31, rolled ring-2
    const char* aw = lf + (size_t)(kg * 32) * 2048 + lane * 16;
    const float* ckw = ck2 + kg * 512 + quad * 4;
    const int kb0 = kg * 512 + quad * 4;

    short8 fa[2][2];
    float4 fc[2];

#define LOADA(slot, t) do {                                              \
    const char* _p = aw + (size_t)(t) * 2048;                            \
    fa[slot][0] = *(const short8*)(_p);                                  \
    fa[slot][1] = *(const short8*)(_p + 1024);                           \
    fc[slot] = *(const float4*)(ckw + (t) * 16);                         \
} while (0)

    float S[4] = {0.f, 0.f, 0.f, 0.f};
    float m1[4], m2[4], m3[4];
    int i1[4], i2[4], i3[4];
#pragma unroll
    for (int bt = 0; bt < 4; ++bt) {
        m1[bt] = -1e30f; m2[bt] = -1e30f; m3[bt] = -1e30f;
        i1[bt] = 0; i2[bt] = 0; i3[bt] = 0;
    }

#define INS(bt, v, kb) do {                                                       \
    bool c1 = (v) > m1[bt], c2 = (v) > m2[bt], c3 = (v) > m3[bt];                 \
    m3[bt] = c2 ? m2[bt] : (c3 ? (v) : m3[bt]);                                   \
    i3[bt] = c2 ? i2[bt] : (c3 ? (kb) : i3[bt]);                                  \
    m2[bt] = c1 ? m1[bt] : (c2 ? (v) : m2[bt]);                                   \
    i2[bt] = c1 ? i1[bt] : (c2 ? (kb) : i2[bt]);                                  \
    m1[bt] = c1 ? (v) : m1[bt];                                                   \
    i1[bt] = c1 ? (kb) : i1[bt];                                                  \
} while (0)

#define COMPUTE(slot, t) do {                                                     \
    v4f acc[4];                                                                   \
    _Pragma("unroll")                                                             \
    for (int bt = 0; bt < 4; ++bt) acc[bt] = (v4f){0.f, 0.f, 0.f, 0.f};           \
    _Pragma("unroll")                                                             \
    for (int bt = 0; bt < 4; ++bt)                                                \
        acc[bt] = __builtin_amdgcn_mfma_f32_16x16x32_bf16(                        \
            fa[slot][0], bh[bt][0], acc[bt], 0, 0, 0);                            \
    _Pragma("unroll")                                                             \
    for (int bt = 0; bt < 4; ++bt)                                                \
        acc[bt] = __builtin_amdgcn_mfma_f32_16x16x32_bf16(                        \
            fa[slot][1], bh[bt][1], acc[bt], 0, 0, 0);                            \
    const int kb = kb0 + (t) * 16;                                                \
    float4 cc = fc[slot];                                                         \
    _Pragma("unroll")                                                             \
    for (int bt = 0; bt < 4; ++bt) {                                              \
        float w0 = fmaf(acc[bt].x, S2C, cc.x);                                    \
        float w1 = fmaf(acc[bt].y, S2C, cc.y);                                    \
        float w2 = fmaf(acc[bt].z, S2C, cc.z);                                    \
        float w3 = fmaf(acc[bt].w, S2C, cc.w);                                    \
        S[bt] += (EXP2(w0) + EXP2(w1)) + (EXP2(w2) + EXP2(w3));                   \
        float v4 = fmaxf(fmaxf(w0, w1), fmaxf(w2, w3));                           \
        INS(bt, v4, kb);                                                          \
    }                                                                             \
} while (0)

    LOADA(0, 0);
    for (int t = 0; t < 32; t += 2) {        // rolled: keeps ring-2 in VGPRs
        LOADA(1, t + 1);
        COMPUTE(0, t);
        int t2 = (t + 2 < 32) ? (t + 2) : 31;
        LOADA(0, t2);
        COMPUTE(1, t + 1);
    }

    // ---- merge the 4 quads (disjoint comp subsets, same sample column)
#pragma unroll
    for (int bt = 0; bt < 4; ++bt) {
#pragma unroll
        for (int d = 16; d <= 32; d <<= 1) {
            S[bt] += __shfl_xor(S[bt], d);
            float M1 = __shfl_xor(m1[bt], d), M2 = __shfl_xor(m2[bt], d),
                  M3 = __shfl_xor(m3[bt], d);
            int   I1 = __shfl_xor(i1[bt], d), I2 = __shfl_xor(i2[bt], d),
                  I3 = __shfl_xor(i3[bt], d);
            INS(bt, M1, I1); INS(bt, M2, I2); INS(bt, M3, I3);
        }
    }
    // lane (quad, n) stores sample-tile bt == quad (disjoint, no predicate)
    {
        int s = quad * 16 + n;
        float sS  = (quad == 0) ? S[0] : (quad == 1) ? S[1] : (quad == 2) ? S[2] : S[3];
        float sm1 = (quad == 0) ? m1[0] : (quad == 1) ? m1[1] : (quad == 2) ? m1[2] : m1[3];
        float sm2 = (quad == 0) ? m2[0] : (quad == 1) ? m2[1] : (quad == 2) ? m2[2] : m2[3];
        float sm3 = (quad == 0) ? m3[0] : (quad == 1) ? m3[1] : (quad == 2) ? m3[2] : m3[3];
        int   si1 = (quad == 0) ? i1[0] : (quad == 1) ? i1[1] : (quad == 2) ? i1[2] : i1[3];
        int   si2 = (quad == 0) ? i2[0] : (quad == 1) ? i2[1] : (quad == 2) ? i2[2] : i2[3];
        int   si3 = (quad == 0) ? i3[0] : (quad == 1) ? i3[1] : (quad == 2) ? i3[2] : i3[3];
        pf[kg][s][0] = sS;  pf[kg][s][1] = sm1; pf[kg][s][2] = sm2; pf[kg][s][3] = sm3;
        pi[kg][s][0] = si1; pi[kg][s][1] = si2; pi[kg][s][2] = si3;
    }
    __syncthreads();

    // ---- merge 4 k-groups (tid<64), write log_prob, stash top-3 bases
    if (tid < 64) {
        float Sx = 0.f, M1 = -1e30f, M2 = -1e30f, M3 = -1e30f;
        int I1 = 0, I2 = 0, I3 = 0;
#pragma unroll
        for (int g = 0; g < 4; ++g) {   // ascending kg => first-tie kept
            Sx += pf[g][tid][0];
            float a1 = pf[g][tid][1], a2 = pf[g][tid][2], a3 = pf[g][tid][3];
            int   b1 = pi[g][tid][0], b2 = pi[g][tid][1], b3 = pi[g][tid][2];
            bool c1 = a1 > M1, c2 = a1 > M2, c3 = a1 > M3;
            M3 = c2 ? M2 : (c3 ? a1 : M3);  I3 = c2 ? I2 : (c3 ? b1 : I3);
            M2 = c1 ? M1 : (c2 ? a1 : M2);  I2 = c1 ? I1 : (c2 ? b1 : I2);
            M1 = c1 ? a1 : M1;              I1 = c1 ? b1 : I1;
            c1 = a2 > M1; c2 = a2 > M2; c3 = a2 > M3;
            M3 = c2 ? M2 : (c3 ? a2 : M3);  I3 = c2 ? I2 : (c3 ? b2 : I3);
            M2 = c1 ? M1 : (c2 ? a2 : M2);  I2 = c1 ? I1 : (c2 ? b2 : I2);
            M1 = c1 ? a2 : M1;              I1 = c1 ? b2 : I1;
            c1 = a3 > M1; c2 = a3 > M2; c3 = a3 > M3;
            M3 = c2 ? M2 : (c3 ? a3 : M3);  I3 = c2 ? I2 : (c3 ? b3 : I3);
            M2 = c1 ? M1 : (c2 ? a3 : M2);  I2 = c1 ? I1 : (c2 ? b3 : I2);
            M1 = c1 ? a3 : M1;              I1 = c1 ? b3 : I1;
        }
        float bias = -xsq_sh[tid] * (1.0f / 128.0f) - LNC;
        out[sbase + tid] = fmaf(__log2f(Sx), LN2F, bias - lse_ptr[0]);
        cb[0][tid] = I1; cb[1][tid] = I2; cb[2][tid] = I3;
    }
    __syncthreads();

    // ---- exact resolution: 12 candidates/sample (3 quad-bases x 4), fp32,
    // first-occurrence (smallest k) tie semantics. 4 threads per sample.
    {
        int s = tid >> 2;        // 0..63
        int j = tid & 3;
        const float4* xrow = (const float4*)(x + (size_t)(sbase + s) * ZD);
        float bestv = -1e30f;
        int bestk = 0x7fffffff;
#pragma unroll
        for (int ci = 0; ci < 3; ++ci) {
            int k = cb[ci][s] + j;
            const float4* lrow = (const float4*)(locs + (size_t)k * ZD);
            float dot = 0.f;
#pragma unroll
            for (int dd = 0; dd < 16; ++dd) {
                float4 xv = xrow[dd];
                float4 lv = lrow[dd];
                dot = fmaf(xv.x, lv.x, dot);
                dot = fmaf(xv.y, lv.y, dot);
                dot = fmaf(xv.z, lv.z, dot);
                dot = fmaf(xv.w, lv.w, dot);
            }
            float v = fmaf(dot, S2C, ck2[k]);
            if (v > bestv || (v == bestv && k < bestk)) { bestv = v; bestk = k; }
        }
#pragma unroll
        for (int d = 1; d <= 2; d <<= 1) {
            float ov = __shfl_xor(bestv, d);
            int   ok = __shfl_xor(bestk, d);
            if (ov > bestv || (ov == bestv && ok < bestk)) { bestv = ov; bestk = ok; }
        }
        if (j == 0) amax_sh[s] = bestk;
    }
    __syncthreads();

    // ---- quantized = locs[argmax], cooperative coalesced float4 writes
    const float4* lq = (const float4*)locs;
    float4* oq = (float4*)(out + N_SAMP + (size_t)sbase * ZD);
#pragma unroll
    for (int i = tid; i < 64 * (ZD / 4); i += 256) {
        int r = i >> 4, c = i & 15;
        oq[i] = lq[(size_t)amax_sh[r] * (ZD / 4) + c];
    }
#undef LOADA
#undef INS
#undef COMPUTE
}

extern "C" void kernel_launch(void* const* d_in, const int* in_sizes, int n_in,
                              void* d_out, int out_size, void* d_ws, size_t ws_size,
                              hipStream_t stream) {
    const float* x      = (const float*)d_in[0];
    const float* locs   = (const float*)d_in[1];
    const float* logits = (const float*)d_in[2];
    float* out = (float*)d_out;

    float* ck2 = (float*)d_ws;                 // 2048 floats
    float* lse = (float*)((char*)d_ws + 8192); // 1 float
    char*  lf  = (char*)d_ws + 16384;          // 256 KB hi-frag array

    prep_kernel<<<65, 256, 0, stream>>>(locs, logits, ck2, lse, lf);
    mix_kernel<<<N_SAMP / 64, 256, 0, stream>>>(x, locs, lf, ck2, lse, out);
}